// Round 6
// baseline (192.633 us; speedup 1.0000x reference)
//
#include <hip/hip_runtime.h>
#include <hip/hip_bf16.h>
#include <cstdint>
#include <math.h>

#define D_DIM 1024
#define TAU_INV 10.0f
#define BK 64
#define NT (D_DIM / BK)        // 16 K-tiles
#define BM 256                 // A-tile rows
#define BN 128                 // B-tile rows (cols of S)
#define SLOT 49152             // per ring slot: A 32K + B 16K

typedef __bf16 bf16x8 __attribute__((ext_vector_type(8)));
typedef float f32x4 __attribute__((ext_vector_type(4)));

#define VMCNT(n) asm volatile("s_waitcnt vmcnt(" #n ")" ::: "memory")
#define BAR() do { asm volatile("" ::: "memory"); \
                   __builtin_amdgcn_s_barrier();  \
                   asm volatile("" ::: "memory"); } while (0)
#define LGKM0() do { asm volatile("s_waitcnt lgkmcnt(0)" ::: "memory"); \
                     __builtin_amdgcn_sched_barrier(0); } while (0)

__device__ __forceinline__ float wave_reduce_add(float v) {
#pragma unroll
    for (int off = 32; off > 0; off >>= 1) v += __shfl_xor(v, off, 64);
    return v;
}

// ---- Kernel A (fused): normalize both rows -> bf16 K, positives, zero rowsum
__global__ __launch_bounds__(256)
void norm_pos_kernel(const float* __restrict__ zi, const float* __restrict__ zj,
                     __hip_bfloat16* __restrict__ K, float* __restrict__ rowsum,
                     float* __restrict__ pos, int n_half) {
    const int i = blockIdx.x;
    const int t = threadIdx.x;                 // 256 threads x 4 floats = 1024
    float4 a = reinterpret_cast<const float4*>(zi + (size_t)i * D_DIM)[t];
    float4 b = reinterpret_cast<const float4*>(zj + (size_t)i * D_DIM)[t];
    float ssa = a.x*a.x + a.y*a.y + a.z*a.z + a.w*a.w;
    float ssb = b.x*b.x + b.y*b.y + b.z*b.z + b.w*b.w;
    float dab = a.x*b.x + a.y*b.y + a.z*b.z + a.w*b.w;
    ssa = wave_reduce_add(ssa);
    ssb = wave_reduce_add(ssb);
    dab = wave_reduce_add(dab);
    __shared__ float wsa[4], wsb[4], wsd[4];
    if ((t & 63) == 0) { wsa[t>>6] = ssa; wsb[t>>6] = ssb; wsd[t>>6] = dab; }
    __syncthreads();
    const float inva = 1.0f / sqrtf(wsa[0] + wsa[1] + wsa[2] + wsa[3]);
    const float invb = 1.0f / sqrtf(wsb[0] + wsb[1] + wsb[2] + wsb[3]);
    union { __hip_bfloat16 h[4]; uint2 u; } pa, pb;
    pa.h[0] = __float2bfloat16(a.x * inva); pa.h[1] = __float2bfloat16(a.y * inva);
    pa.h[2] = __float2bfloat16(a.z * inva); pa.h[3] = __float2bfloat16(a.w * inva);
    pb.h[0] = __float2bfloat16(b.x * invb); pb.h[1] = __float2bfloat16(b.y * invb);
    pb.h[2] = __float2bfloat16(b.z * invb); pb.h[3] = __float2bfloat16(b.w * invb);
    reinterpret_cast<uint2*>(K + (size_t)i * D_DIM)[t] = pa.u;
    reinterpret_cast<uint2*>(K + (size_t)(i + n_half) * D_DIM)[t] = pb.u;
    if (t == 0) {
        pos[i] = (wsd[0] + wsd[1] + wsd[2] + wsd[3]) * inva * invb;
        rowsum[i] = 0.0f;
        rowsum[i + n_half] = 0.0f;
    }
}

// ---- Kernel B: triangular 256x128 tiles of S = K K^T, phase-locked schedule
// Tiles: by in [0,32) over 256-row blocks, bx in [2*by, 64) over 128-col
// blocks -> 1056 jobs (1.21x tail factor at 1 block/CU vs 1.45x for 528).
// "diag" tiles (bx>>1 == by): row-reduction only, exact diagonal zeroed
// (each within-block pair appears twice). Others: row + column reduction.
//
// 8 waves (2M x 4N); per-wave 128x32 output, split into 2 quadrants (a=0,1)
// of 64x32 = acc[a][4][2]; 16 MFMA per quadrant-phase. BK=64, ring-3 LDS
// (3 x 48 KiB = 144 KiB): compute tile t from slot t%3 while staging tile
// t+2 into slot (t+2)%3 (tile t+1 fully in flight).
//
// Guarantee chain (cross-wave residency): at ph1 of tile t every wave does
// VMCNT(6) -- its 6 newest loads are exactly tile t+2's -- then BAR, which
// publishes tile t+1 to all waves. Reads of tile t at ph0/ph1 are covered by
// the pair executed during tile t-1. ds_reads are issued BEFORE the barrier
// (complete during barrier wait); LGKM0 after the barrier yields a clean
// 16-MFMA setprio cluster (T3+T4+T5).
//
// LDS swizzle (verified 0-conflict r2-r5): 16B slot_phys = slot_log ^ (row&7),
// inverse-applied on the global staging source (rule #21).
__global__ __launch_bounds__(512, 2)
void simclr_gemm_kernel(const __hip_bfloat16* __restrict__ Kmat,
                        float* __restrict__ rowsum, int n_total) {
    __shared__ char lds[147456];

    const int tid  = threadIdx.x;
    const int lane = tid & 63;
    const int wave = tid >> 6;          // 0..7
    const int wr = wave >> 2;           // 0..1  (A rows wr*128)
    const int wc = wave & 3;            // 0..3  (B cols wc*32)
    const int kgrp = lane >> 4;         // 16B k-slot group

    // bijective XCD swizzle: nwg = 1056 = 8 * 132
    const int wg = (blockIdx.x & 7) * 132 + (blockIdx.x >> 3);

    // decode wg -> (by, bx): by in [0,32), bx in [2*by, 64)
    int by = 0, start = 0;
    while (wg >= start + (64 - 2 * by)) { start += 64 - 2 * by; ++by; }
    const int bx = 2 * by + (wg - start);
    const bool diag = ((bx >> 1) == by);
    const int rowbase = by * BM;
    const int colbase = bx * BN;

    const char* gK = reinterpret_cast<const char*>(Kmat);
    const int srow = tid >> 3;                          // 0..63
    const int sswz = (tid & 7) ^ (srow & 7);            // inverse-swizzled slot

    // stage A rows 0..255 of K-tile tt (4 loads/thread)
    auto stage_A = [&](int tt) {
        const int s = tt % 3;
        const size_t kbyte = (size_t)tt * (BK * 2);
        char* dst = lds + s * SLOT + tid * 16;
#pragma unroll
        for (int i = 0; i < 4; ++i) {
            const int row = i * 64 + srow;
            const char* src = gK + (size_t)(rowbase + row) * (D_DIM * 2) + kbyte + sswz * 16;
            __builtin_amdgcn_global_load_lds(
                (const __attribute__((address_space(1))) void*)src,
                (__attribute__((address_space(3))) void*)(dst + i * 8192),
                16, 0, 0);
        }
    };
    // stage B rows 0..127 of K-tile tt (2 loads/thread)
    auto stage_B = [&](int tt) {
        const int s = tt % 3;
        const size_t kbyte = (size_t)tt * (BK * 2);
        char* dst = lds + s * SLOT + 32768 + tid * 16;
#pragma unroll
        for (int i = 0; i < 2; ++i) {
            const int row = i * 64 + srow;
            const char* src = gK + (size_t)(colbase + row) * (D_DIM * 2) + kbyte + sswz * 16;
            __builtin_amdgcn_global_load_lds(
                (const __attribute__((address_space(1))) void*)src,
                (__attribute__((address_space(3))) void*)(dst + i * 8192),
                16, 0, 0);
        }
    };

    f32x4 acc[2][4][2] = {};
    bf16x8 af[8], bf[4];

    auto readA = [&](int s, int a) {
        const char* Ab = lds + s * SLOT;
#pragma unroll
        for (int mi = 0; mi < 4; ++mi) {
            const int row = wr * 128 + a * 64 + mi * 16 + (lane & 15);
#pragma unroll
            for (int kk = 0; kk < 2; ++kk)
                af[mi * 2 + kk] = *reinterpret_cast<const bf16x8*>(
                    Ab + row * 128 + (((kk * 4 + kgrp) ^ (row & 7)) << 4));
        }
    };
    auto readB = [&](int s) {
        const char* Bb = lds + s * SLOT + 32768;
#pragma unroll
        for (int ni = 0; ni < 2; ++ni) {
            const int row = wc * 32 + ni * 16 + (lane & 15);
#pragma unroll
            for (int kk = 0; kk < 2; ++kk)
                bf[ni * 2 + kk] = *reinterpret_cast<const bf16x8*>(
                    Bb + row * 128 + (((kk * 4 + kgrp) ^ (row & 7)) << 4));
        }
    };
    auto mmaq = [&](int a) {
        __builtin_amdgcn_s_setprio(1);
#pragma unroll
        for (int kk = 0; kk < 2; ++kk)       // kk outer: 8 independent chains
#pragma unroll
            for (int mi = 0; mi < 4; ++mi)
#pragma unroll
                for (int ni = 0; ni < 2; ++ni)
                    acc[a][mi][ni] = __builtin_amdgcn_mfma_f32_16x16x32_bf16(
                        af[mi * 2 + kk], bf[ni * 2 + kk], acc[a][mi][ni], 0, 0, 0);
        __builtin_amdgcn_s_setprio(0);
    };

    // prologue: tiles 0 and 1 in flight; publish tile 0
    stage_A(0); stage_B(0); stage_A(1); stage_B(1);
    VMCNT(6); BAR();

    for (int t = 0; t < NT; ++t) {
        const int s = t % 3;
        // ---- phase 0: quadrant a=0 (reads covered by tile t-1's vmcnt+BAR)
        readB(s); readA(s, 0);
        if (t + 2 < NT) stage_A(t + 2);
        BAR(); LGKM0();
        mmaq(0);
        BAR();
        // ---- phase 1: quadrant a=1
        readA(s, 1);
        if (t + 2 < NT) stage_B(t + 2);
        if (t < NT - 2)      { VMCNT(6); }   // publish tile t+1 at next BAR
        else if (t == NT - 2){ VMCNT(0); }   // publish final tile
        BAR(); LGKM0();
        mmaq(1);
        BAR();
    }

    // Epilogue. C-frag: col = lane&15, row = (lane>>4)*4 + reg.
    float colpart[2] = {0.0f, 0.0f};
#pragma unroll
    for (int a = 0; a < 2; ++a) {
#pragma unroll
        for (int mi = 0; mi < 4; ++mi) {
#pragma unroll
            for (int reg = 0; reg < 4; ++reg) {
                const int grow = rowbase + wr * 128 + a * 64 + mi * 16 +
                                 ((lane >> 4) << 2) + reg;
                float rowpart = 0.0f;
#pragma unroll
                for (int ni = 0; ni < 2; ++ni) {
                    const int gcol = colbase + wc * 32 + ni * 16 + (lane & 15);
                    float e = __expf(acc[a][mi][ni][reg] * TAU_INV);
                    if (diag && grow == gcol) e = 0.0f;
                    rowpart += e;
                    colpart[ni] += e;
                }
#pragma unroll
                for (int off = 1; off < 16; off <<= 1)
                    rowpart += __shfl_xor(rowpart, off, 64);
                if ((lane & 15) == 0) atomicAdd(&rowsum[grow], rowpart);
            }
        }
    }
    if (!diag) {
#pragma unroll
        for (int ni = 0; ni < 2; ++ni) {
            float cp = colpart[ni];
            cp += __shfl_xor(cp, 16, 64);
            cp += __shfl_xor(cp, 32, 64);
            if (lane < 16)
                atomicAdd(&rowsum[colbase + wc * 32 + ni * 16 + lane], cp);
        }
    }
}

// ---- Kernel C: loss = mean(log(denom) - pos/tau) ---------------------------
__global__ __launch_bounds__(256)
void loss_kernel(const float* __restrict__ rowsum, const float* __restrict__ pos,
                 float* __restrict__ out, int n_total, int n_half) {
    const int t = threadIdx.x;
    float acc = 0.0f;
    for (int r = t; r < n_total; r += 256) {
        const int pi = (r < n_half) ? r : (r - n_half);
        acc += logf(rowsum[r]) - TAU_INV * pos[pi];
    }
    acc = wave_reduce_add(acc);
    __shared__ float ws4[4];
    if ((t & 63) == 0) ws4[t >> 6] = acc;
    __syncthreads();
    if (t == 0) out[0] = (ws4[0] + ws4[1] + ws4[2] + ws4[3]) / (float)n_total;
}

extern "C" void kernel_launch(void* const* d_in, const int* in_sizes, int n_in,
                              void* d_out, int out_size, void* d_ws, size_t ws_size,
                              hipStream_t stream) {
    const float* zi = (const float*)d_in[0];
    const float* zj = (const float*)d_in[1];
    float* out = (float*)d_out;

    const int n_half  = in_sizes[0] / D_DIM;   // 4096
    const int n_total = 2 * n_half;            // 8192

    char* ws = (char*)d_ws;
    __hip_bfloat16* K = (__hip_bfloat16*)ws;
    size_t off = (size_t)n_total * D_DIM * sizeof(__hip_bfloat16);
    float* rowsum = (float*)(ws + off); off += (size_t)n_total * 4;
    float* pos    = (float*)(ws + off); off += (size_t)n_half * 4;

    norm_pos_kernel<<<n_half, 256, 0, stream>>>(zi, zj, K, rowsum, pos, n_half);

    // triangular 256x128 tiles: sum_{by=0}^{31} (64 - 2*by) = 1056 blocks
    simclr_gemm_kernel<<<1056, 512, 0, stream>>>(K, rowsum, n_total);

    loss_kernel<<<1, 256, 0, stream>>>(rowsum, pos, out, n_total, n_half);
}

// Round 7
// 123.535 us; speedup vs baseline: 1.5593x; 1.5593x over previous
//
#include <hip/hip_runtime.h>
#include <hip/hip_bf16.h>
#include <cstdint>
#include <math.h>

#define D_DIM 1024
#define TAU_INV 10.0f
#define BK 32
#define NT (D_DIM / BK)        // 32 K-tiles
#define BM 256                 // A-tile rows
#define BN 128                 // B-tile rows (cols of S)
#define SLOT 24576             // ring slot: A 16K + B 8K

typedef __bf16 bf16x8 __attribute__((ext_vector_type(8)));
typedef float f32x4 __attribute__((ext_vector_type(4)));

#define VMCNT(n) asm volatile("s_waitcnt vmcnt(" #n ")" ::: "memory")
#define BAR() do { asm volatile("" ::: "memory"); \
                   __builtin_amdgcn_s_barrier();  \
                   asm volatile("" ::: "memory"); } while (0)
#define LGKM0() do { asm volatile("s_waitcnt lgkmcnt(0)" ::: "memory"); \
                     __builtin_amdgcn_sched_barrier(0); } while (0)

__device__ __forceinline__ float wave_reduce_add(float v) {
#pragma unroll
    for (int off = 32; off > 0; off >>= 1) v += __shfl_xor(v, off, 64);
    return v;
}

// ---- Kernel A (fused): normalize both rows -> bf16 K, positives, zero rowsum
__global__ __launch_bounds__(256)
void norm_pos_kernel(const float* __restrict__ zi, const float* __restrict__ zj,
                     __hip_bfloat16* __restrict__ K, float* __restrict__ rowsum,
                     float* __restrict__ pos, int n_half) {
    const int i = blockIdx.x;
    const int t = threadIdx.x;                 // 256 threads x 4 floats = 1024
    float4 a = reinterpret_cast<const float4*>(zi + (size_t)i * D_DIM)[t];
    float4 b = reinterpret_cast<const float4*>(zj + (size_t)i * D_DIM)[t];
    float ssa = a.x*a.x + a.y*a.y + a.z*a.z + a.w*a.w;
    float ssb = b.x*b.x + b.y*b.y + b.z*b.z + b.w*b.w;
    float dab = a.x*b.x + a.y*b.y + a.z*b.z + a.w*b.w;
    ssa = wave_reduce_add(ssa);
    ssb = wave_reduce_add(ssb);
    dab = wave_reduce_add(dab);
    __shared__ float wsa[4], wsb[4], wsd[4];
    if ((t & 63) == 0) { wsa[t>>6] = ssa; wsb[t>>6] = ssb; wsd[t>>6] = dab; }
    __syncthreads();
    const float inva = 1.0f / sqrtf(wsa[0] + wsa[1] + wsa[2] + wsa[3]);
    const float invb = 1.0f / sqrtf(wsb[0] + wsb[1] + wsb[2] + wsb[3]);
    union { __hip_bfloat16 h[4]; uint2 u; } pa, pb;
    pa.h[0] = __float2bfloat16(a.x * inva); pa.h[1] = __float2bfloat16(a.y * inva);
    pa.h[2] = __float2bfloat16(a.z * inva); pa.h[3] = __float2bfloat16(a.w * inva);
    pb.h[0] = __float2bfloat16(b.x * invb); pb.h[1] = __float2bfloat16(b.y * invb);
    pb.h[2] = __float2bfloat16(b.z * invb); pb.h[3] = __float2bfloat16(b.w * invb);
    reinterpret_cast<uint2*>(K + (size_t)i * D_DIM)[t] = pa.u;
    reinterpret_cast<uint2*>(K + (size_t)(i + n_half) * D_DIM)[t] = pb.u;
    if (t == 0) {
        pos[i] = (wsd[0] + wsd[1] + wsd[2] + wsd[3]) * inva * invb;
        rowsum[i] = 0.0f;
        rowsum[i + n_half] = 0.0f;
    }
}

// ---- Kernel B: triangular 256x128 tiles of S = K K^T, 2-phase pipeline -----
// Tiles: by in [0,32), bx in [2*by, 64) -> 1056 jobs. diag (bx>>1==by):
// row-reduction only, exact diagonal zeroed; others: row + col reduction.
//
// 4 waves (2M x 2N), per-wave output 128x64 = acc[2(Ahalf)][4][4]; MFMA:LDS
// per K-tile per wave = 32 MFMA (155 cyc SIMD) : 12 ds_read_b128 (144 cyc CU)
// -> MFMA-bound per wave. BK=32, ring-3 LDS (3 x 24 KiB = 72 KiB) -> 2
// blocks/CU: two independent barrier domains co-schedule (m114).
//
// Schedule per K-tile t (slot s = t%3):
//   ph0: readB(4) + readA(half0, 4)  [tile t resident: published at ph1(t-1)]
//        BAR ; lgkmcnt(0)+sched_barrier ; setprio(1) 16 MFMA setprio(0)
//   ph1: readA(half1, 4) ; stage tile t+2 (6 gloads, slot (t-1)%3)
//        vmcnt(6) [publishes tile t+1: leaves only stage(t+2) outstanding]
//        BAR ; lgkmcnt(0)+sched_barrier ; setprio(1) 16 MFMA setprio(0)
// Write-after-read safety: stage(t+2)@ph1(t) targets slot (t-1)%3, last read
// at ph1(t-1); every wave's those reads complete at its LGKM0(ph1,t-1), which
// precedes its arrival at BAR(ph0,t); stage is issued after BAR(ph0,t).
// Epilogue waits: vmcnt(6) while stages remain, vmcnt(0) at t==NT-2.
// LDS swizzle (R4-verified, 0 conflicts): 16B slot_phys = kgrp ^ ((row>>1)&3),
// inverse-applied on the global staging source (rule #21).
__global__ __launch_bounds__(256, 2)
void simclr_gemm_kernel(const __hip_bfloat16* __restrict__ Kmat,
                        float* __restrict__ rowsum, int n_total) {
    __shared__ char lds[73728];

    const int tid  = threadIdx.x;
    const int lane = tid & 63;
    const int wave = tid >> 6;          // 0..3
    const int wr = wave >> 1;           // 0..1  (A rows wr*128)
    const int wc = wave & 1;            // 0..1  (B cols wc*64)
    const int kgrp = lane >> 4;         // 16B k-slot within 64B row

    // bijective XCD swizzle: nwg = 1056 = 8 * 132
    const int wg = (blockIdx.x & 7) * 132 + (blockIdx.x >> 3);

    // decode wg -> (by, bx): by in [0,32), bx in [2*by, 64)
    int by = 0, start = 0;
    while (wg >= start + (64 - 2 * by)) { start += 64 - 2 * by; ++by; }
    const int bx = 2 * by + (wg - start);
    const bool diag = ((bx >> 1) == by);
    const int rowbase = by * BM;
    const int colbase = bx * BN;

    const char* gK = reinterpret_cast<const char*>(Kmat);
    const int srow = tid >> 2;                          // 0..63 per 4KB chunk
    const int sswz = (tid & 3) ^ ((srow >> 1) & 3);     // inverse-swizzled slot

    // stage full K-tile tt into ring slot tt%3: A 4 chunks + B 2 chunks
    auto stage_all = [&](int tt) {
        const int s = tt % 3;
        const size_t kbyte = (size_t)tt * (BK * 2);     // 64 B per row chunk
        char* dstA = lds + s * SLOT + tid * 16;
        char* dstB = lds + s * SLOT + 16384 + tid * 16;
#pragma unroll
        for (int i = 0; i < 4; ++i) {
            const int row = i * 64 + srow;
            const char* src = gK + (size_t)(rowbase + row) * (D_DIM * 2) + kbyte + sswz * 16;
            __builtin_amdgcn_global_load_lds(
                (const __attribute__((address_space(1))) void*)src,
                (__attribute__((address_space(3))) void*)(dstA + i * 4096),
                16, 0, 0);
        }
#pragma unroll
        for (int i = 0; i < 2; ++i) {
            const int row = i * 64 + srow;
            const char* src = gK + (size_t)(colbase + row) * (D_DIM * 2) + kbyte + sswz * 16;
            __builtin_amdgcn_global_load_lds(
                (const __attribute__((address_space(1))) void*)src,
                (__attribute__((address_space(3))) void*)(dstB + i * 4096),
                16, 0, 0);
        }
    };

    f32x4 acc[2][4][4] = {};   // [A-half][mi][ni]
    bf16x8 af[4], bf[4];

    auto readA = [&](int s, int a) {
        const char* Ab = lds + s * SLOT;
#pragma unroll
        for (int mi = 0; mi < 4; ++mi) {
            const int row = wr * 128 + a * 64 + mi * 16 + (lane & 15);
            af[mi] = *reinterpret_cast<const bf16x8*>(
                Ab + row * 64 + ((kgrp ^ ((row >> 1) & 3)) << 4));
        }
    };
    auto readB = [&](int s) {
        const char* Bb = lds + s * SLOT + 16384;
#pragma unroll
        for (int ni = 0; ni < 4; ++ni) {
            const int row = wc * 64 + ni * 16 + (lane & 15);
            bf[ni] = *reinterpret_cast<const bf16x8*>(
                Bb + row * 64 + ((kgrp ^ ((row >> 1) & 3)) << 4));
        }
    };
    auto mmaq = [&](int a) {
        __builtin_amdgcn_s_setprio(1);
#pragma unroll
        for (int mi = 0; mi < 4; ++mi)
#pragma unroll
            for (int ni = 0; ni < 4; ++ni)
                acc[a][mi][ni] = __builtin_amdgcn_mfma_f32_16x16x32_bf16(
                    af[mi], bf[ni], acc[a][mi][ni], 0, 0, 0);
        __builtin_amdgcn_s_setprio(0);
    };

    // prologue: tiles 0,1 staged; publish tile 0 (leave tile 1's 6 in flight)
    stage_all(0); stage_all(1);
    VMCNT(6); BAR();

    for (int t = 0; t < NT; ++t) {
        const int s = t % 3;
        // ---- phase 0: A-half 0 (+ B for whole K-tile)
        readB(s); readA(s, 0);
        BAR(); LGKM0();
        mmaq(0);
        // ---- phase 1: A-half 1; stage t+2; publish t+1
        readA(s, 1);
        if (t + 2 < NT) stage_all(t + 2);
        if (t < NT - 2)       { VMCNT(6); }
        else if (t == NT - 2) { VMCNT(0); }
        BAR(); LGKM0();
        mmaq(1);
    }

    // Epilogue. C-frag: col = lane&15, row = (lane>>4)*4 + reg.
    float colpart[4] = {0.0f, 0.0f, 0.0f, 0.0f};
#pragma unroll
    for (int a = 0; a < 2; ++a) {
#pragma unroll
        for (int mi = 0; mi < 4; ++mi) {
#pragma unroll
            for (int reg = 0; reg < 4; ++reg) {
                const int grow = rowbase + wr * 128 + a * 64 + mi * 16 +
                                 ((lane >> 4) << 2) + reg;
                float rowpart = 0.0f;
#pragma unroll
                for (int ni = 0; ni < 4; ++ni) {
                    const int gcol = colbase + wc * 64 + ni * 16 + (lane & 15);
                    float e = __expf(acc[a][mi][ni][reg] * TAU_INV);
                    if (diag && grow == gcol) e = 0.0f;
                    rowpart += e;
                    colpart[ni] += e;
                }
#pragma unroll
                for (int off = 1; off < 16; off <<= 1)
                    rowpart += __shfl_xor(rowpart, off, 64);
                if ((lane & 15) == 0) atomicAdd(&rowsum[grow], rowpart);
            }
        }
    }
    if (!diag) {
#pragma unroll
        for (int ni = 0; ni < 4; ++ni) {
            float cp = colpart[ni];
            cp += __shfl_xor(cp, 16, 64);
            cp += __shfl_xor(cp, 32, 64);
            if (lane < 16)
                atomicAdd(&rowsum[colbase + wc * 64 + ni * 16 + lane], cp);
        }
    }
}

// ---- Kernel C: loss = mean(log(denom) - pos/tau) ---------------------------
__global__ __launch_bounds__(256)
void loss_kernel(const float* __restrict__ rowsum, const float* __restrict__ pos,
                 float* __restrict__ out, int n_total, int n_half) {
    const int t = threadIdx.x;
    float acc = 0.0f;
    for (int r = t; r < n_total; r += 256) {
        const int pi = (r < n_half) ? r : (r - n_half);
        acc += logf(rowsum[r]) - TAU_INV * pos[pi];
    }
    acc = wave_reduce_add(acc);
    __shared__ float ws4[4];
    if ((t & 63) == 0) ws4[t >> 6] = acc;
    __syncthreads();
    if (t == 0) out[0] = (ws4[0] + ws4[1] + ws4[2] + ws4[3]) / (float)n_total;
}

extern "C" void kernel_launch(void* const* d_in, const int* in_sizes, int n_in,
                              void* d_out, int out_size, void* d_ws, size_t ws_size,
                              hipStream_t stream) {
    const float* zi = (const float*)d_in[0];
    const float* zj = (const float*)d_in[1];
    float* out = (float*)d_out;

    const int n_half  = in_sizes[0] / D_DIM;   // 4096
    const int n_total = 2 * n_half;            // 8192

    char* ws = (char*)d_ws;
    __hip_bfloat16* K = (__hip_bfloat16*)ws;
    size_t off = (size_t)n_total * D_DIM * sizeof(__hip_bfloat16);
    float* rowsum = (float*)(ws + off); off += (size_t)n_total * 4;
    float* pos    = (float*)(ws + off); off += (size_t)n_half * 4;

    norm_pos_kernel<<<n_half, 256, 0, stream>>>(zi, zj, K, rowsum, pos, n_half);

    // triangular 256x128 tiles: sum_{by=0}^{31} (64 - 2*by) = 1056 blocks
    simclr_gemm_kernel<<<1056, 256, 0, stream>>>(K, rowsum, n_total);

    loss_kernel<<<1, 256, 0, stream>>>(rowsum, pos, out, n_total, n_half);
}